// Round 1
// baseline (1730.761 us; speedup 1.0000x reference)
//
#include <hip/hip_runtime.h>
#include <hip/hip_bf16.h>
#include <stdint.h>

// Problem constants
#define DD   768
#define NH   8
#define HDIM 96
#define NS   23
#define NL   50
#define NB   4096

typedef float  floatx4 __attribute__((ext_vector_type(4)));
typedef __bf16 bf16x8  __attribute__((ext_vector_type(8)));

__device__ __forceinline__ unsigned short f2bf(float x) {
  unsigned int u = __float_as_uint(x);
  u += 0x7fffu + ((u >> 16) & 1u);          // RNE, no NaN handling (inputs are Gaussian)
  return (unsigned short)(u >> 16);
}
__device__ __forceinline__ float bf2f(unsigned short v) {
  return __uint_as_float(((unsigned int)v) << 16);
}

union BV { bf16x8 v; unsigned short s[8]; };

// ---------------- precompute kernels (all tiny) ----------------
// q_miss[s,d] = in_proj_w[d,:] . missing_table[s,:] + in_proj_b[d]   (queries of missing sections)
__global__ void k_qmiss(const float* __restrict__ ipw, const float* __restrict__ ipb,
                        const float* __restrict__ mt, float* __restrict__ qm) {
  int o = blockIdx.x * 256 + threadIdx.x;   // 23*768 = 17664 = 69*256 exact
  int s = o / DD, d = o - s * DD;
  const float* wr = ipw + (size_t)d * DD;
  const float* mr = mt + (size_t)s * DD;
  float sum = ipb[d];
  for (int j = 0; j < DD; ++j) sum += wr[j] * mr[j];
  qm[o] = sum;
}

// wop[l,d] = sum_j pred_w[l,j] * out_proj_w[j,d]   (out_proj folded into predictor)
__global__ void k_wop(const float* __restrict__ pw, const float* __restrict__ opw,
                      float* __restrict__ wop) {
  int o = blockIdx.x * 256 + threadIdx.x;   // 50*768 = 38400 = 150*256 exact
  int l = o / DD, d = o - l * DD;
  const float* pr = pw + (size_t)l * DD;
  float sum = 0.f;
  for (int j = 0; j < DD; ++j) sum += pr[j] * opw[(size_t)j * DD + d];
  wop[o] = sum;
}

// bop[l] = pred_w[l,:] . out_proj_b
__global__ void k_bop(const float* __restrict__ pw, const float* __restrict__ opb,
                      float* __restrict__ bop) {
  int l = threadIdx.x;
  if (l < NL) {
    const float* pr = pw + (size_t)l * DD;
    float sum = 0.f;
    for (int j = 0; j < DD; ++j) sum += pr[j] * opb[j];
    bop[l] = sum;
  }
}

// ---------------- K/V projection GEMM ----------------
// C[m, 0:768] = K row m, C[m, 768:1536] = V row m  (bf16), m over chunk rows.
// A = cls chunk [Mrows,768] fp32 (converted to bf16 in staging), W = in_proj_w rows 768..2303 [1536,768].
// 128x128 tile, 4 waves each 64x64 via 4x4 grid of 16x16x32 bf16 MFMA, BK=32, 2-barrier K-loop.
__global__ __launch_bounds__(256, 2) void kv_gemm(
    const float* __restrict__ A, const float* __restrict__ W,
    const float* __restrict__ bias, unsigned short* __restrict__ C, int Mrows) {
  __shared__ __align__(16) unsigned short As[128 * 32];
  __shared__ __align__(16) unsigned short Bs[128 * 32];
  const int tid = threadIdx.x;
  const int wave = tid >> 6, lane = tid & 63;
  const int wm = wave >> 1, wn = wave & 1;
  const int lq = lane >> 4, lr = lane & 15;
  (void)Mrows;

  floatx4 acc[4][4];
#pragma unroll
  for (int a = 0; a < 4; ++a)
#pragma unroll
    for (int b = 0; b < 4; ++b) {
      acc[a][b][0] = 0.f; acc[a][b][1] = 0.f; acc[a][b][2] = 0.f; acc[a][b][3] = 0.f;
    }

  // staging: 512 chunks of 8 bf16 per tile (128 rows x 4 k-chunks), 2 passes of 256 threads
  const float* ap[2]; const float* bp[2];
  unsigned short* as_[2]; unsigned short* bs_[2];
#pragma unroll
  for (int p = 0; p < 2; ++p) {
    int c = p * 256 + tid;
    int row = c >> 2, kc = c & 3;
    ap[p] = A + (size_t)(blockIdx.x * 128 + row) * DD + kc * 8;
    bp[p] = W + (size_t)(blockIdx.y * 128 + row) * DD + kc * 8;
    as_[p] = &As[c * 8];
    bs_[p] = &Bs[c * 8];
  }

  for (int k0 = 0; k0 < DD; k0 += 32) {
#pragma unroll
    for (int p = 0; p < 2; ++p) {
      float4 a0 = *(const float4*)(ap[p] + k0);
      float4 a1 = *(const float4*)(ap[p] + k0 + 4);
      BV ua;
      ua.s[0] = f2bf(a0.x); ua.s[1] = f2bf(a0.y); ua.s[2] = f2bf(a0.z); ua.s[3] = f2bf(a0.w);
      ua.s[4] = f2bf(a1.x); ua.s[5] = f2bf(a1.y); ua.s[6] = f2bf(a1.z); ua.s[7] = f2bf(a1.w);
      *(bf16x8*)as_[p] = ua.v;
      float4 b0 = *(const float4*)(bp[p] + k0);
      float4 b1 = *(const float4*)(bp[p] + k0 + 4);
      BV ub;
      ub.s[0] = f2bf(b0.x); ub.s[1] = f2bf(b0.y); ub.s[2] = f2bf(b0.z); ub.s[3] = f2bf(b0.w);
      ub.s[4] = f2bf(b1.x); ub.s[5] = f2bf(b1.y); ub.s[6] = f2bf(b1.z); ub.s[7] = f2bf(b1.w);
      *(bf16x8*)bs_[p] = ub.v;
    }
    __syncthreads();
    bf16x8 af[4], bq[4];
#pragma unroll
    for (int t = 0; t < 4; ++t) {
      af[t] = *(bf16x8*)&As[(wm * 64 + t * 16 + lr) * 32 + lq * 8];
      bq[t] = *(bf16x8*)&Bs[(wn * 64 + t * 16 + lr) * 32 + lq * 8];
    }
#pragma unroll
    for (int mt = 0; mt < 4; ++mt)
#pragma unroll
      for (int nt = 0; nt < 4; ++nt)
        acc[mt][nt] = __builtin_amdgcn_mfma_f32_16x16x32_bf16(af[mt], bq[nt], acc[mt][nt], 0, 0, 0);
    __syncthreads();
  }

  // epilogue: D[row=(lane>>4)*4+i][col=lane&15] per 16x16 tile (verified m89/m91 layout)
  const int bm = blockIdx.x * 128 + wm * 64;
  const int bn = blockIdx.y * 128 + wn * 64;
#pragma unroll
  for (int nt = 0; nt < 4; ++nt) {
    int col = bn + nt * 16 + lr;
    float bb = bias[col];
#pragma unroll
    for (int mt = 0; mt < 4; ++mt) {
#pragma unroll
      for (int i = 0; i < 4; ++i) {
        int row = bm + mt * 16 + lq * 4 + i;
        C[(size_t)row * 1536 + col] = f2bf(acc[mt][nt][i] + bb);
      }
    }
  }
}

// ---------------- per-sample attention + folded epilogue ----------------
// logits[b] = pred_b + (acc.pred_w + cacc.wop + nu*bop)/23
//   acc  = sum of existing cls rows (or sum of missing_table rows if no section exists)
//   cacc = sum over missing sections of ctx (attention output before out_proj)
__global__ __launch_bounds__(256, 2) void attn_logits(
    const float* __restrict__ cls, const float* __restrict__ mtab,
    const unsigned short* __restrict__ KV, const float* __restrict__ qmiss,
    const float* __restrict__ wop, const float* __restrict__ bop,
    const float* __restrict__ predw, const float* __restrict__ predb,
    const int* __restrict__ exist, float* __restrict__ out, int b0) {
  const int tid = threadIdx.x;
  const int bl = blockIdx.x;
  const int b = b0 + bl;

  __shared__ __align__(16) unsigned short Kl[NS][776];  // +8 pad: 16B-aligned rows, bank spread
  __shared__ __align__(16) unsigned short Vl[NS][776];
  __shared__ __align__(16) float q_s[832];              // q staged at stride 104/head (bank spread); reused as acc
  __shared__ __align__(16) float c_s[768];              // cacc at the end
  __shared__ float attnw[NS][8];
  __shared__ int elist[NS], ulist[NS];
  __shared__ int meta[3];

  if (tid == 0) {
    int ne = 0, nu = 0;
    for (int s = 0; s < NS; ++s) {
      if (exist[(size_t)b * NS + s] != 0) elist[ne++] = s;
      else ulist[nu++] = s;
    }
    meta[0] = ne; meta[1] = nu; meta[2] = (ne > 0) ? 1 : 0;
  }
  __syncthreads();
  const int ne = meta[0], nu = meta[1], hasany = meta[2];

  // stage K,V of existing sections (compacted) into LDS: 192 int4 chunks per section
  for (int c = tid; c < ne * 192; c += 256) {
    int i = c / 192, t = c - i * 192;
    const int4* src = (const int4*)(KV + ((size_t)bl * NS + elist[i]) * 1536);
    int4 val = src[t];
    if (t < 96) *(int4*)&Kl[i][t * 8] = val;
    else        *(int4*)&Vl[i][(t - 96) * 8] = val;
  }

  // acc (fp32, exact): each thread owns d = tid, tid+256, tid+512
  float ac0 = 0.f, ac1 = 0.f, ac2 = 0.f;
  if (hasany) {
    for (int i = 0; i < ne; ++i) {
      const float* r = cls + ((size_t)b * NS + elist[i]) * DD;
      ac0 += r[tid]; ac1 += r[tid + 256]; ac2 += r[tid + 512];
    }
  } else {
    for (int s = 0; s < NS; ++s) {
      const float* r = mtab + (size_t)s * DD;
      ac0 += r[tid]; ac1 += r[tid + 256]; ac2 += r[tid + 512];
    }
  }
  float cc0 = 0.f, cc1 = 0.f, cc2 = 0.f;
  __syncthreads();  // KV staging complete

  if (hasany) {
    const int h0 = tid / 96, h1 = (tid + 256) / 96, h2 = (tid + 512) / 96;
    for (int uu = 0; uu < nu; ++uu) {
      const int sq = ulist[uu];
      for (int d = tid; d < DD; d += 256) {
        int h = d / 96, r = d - h * 96;
        q_s[h * 104 + r] = qmiss[(size_t)sq * DD + d];
      }
      __syncthreads();
      // scores: thread (h = tid&7, i = tid>>3), vectorized LDS reads
      if (tid < 8 * ne) {
        const int h = tid & 7, i = tid >> 3;
        const int4* kp = (const int4*)&Kl[i][h * 96];
        const float4* qp = (const float4*)&q_s[h * 104];
        float sc = 0.f;
#pragma unroll
        for (int c4 = 0; c4 < 12; ++c4) {
          int4 kk = kp[c4];
          float4 q0 = qp[2 * c4];
          float4 q1 = qp[2 * c4 + 1];
          sc += q0.x * bf2f((unsigned short)(((unsigned)kk.x) & 0xffffu));
          sc += q0.y * bf2f((unsigned short)(((unsigned)kk.x) >> 16));
          sc += q0.z * bf2f((unsigned short)(((unsigned)kk.y) & 0xffffu));
          sc += q0.w * bf2f((unsigned short)(((unsigned)kk.y) >> 16));
          sc += q1.x * bf2f((unsigned short)(((unsigned)kk.z) & 0xffffu));
          sc += q1.y * bf2f((unsigned short)(((unsigned)kk.z) >> 16));
          sc += q1.z * bf2f((unsigned short)(((unsigned)kk.w) & 0xffffu));
          sc += q1.w * bf2f((unsigned short)(((unsigned)kk.w) >> 16));
        }
        attnw[i][h] = sc * 0.10206207261596575f;  // 96^-0.5
      }
      __syncthreads();
      // softmax over existing keys only (== reference: masked keys underflow to exactly 0)
      if (tid < 8) {
        float mx = -1e30f;
        for (int i = 0; i < ne; ++i) mx = fmaxf(mx, attnw[i][tid]);
        float sm = 0.f;
        for (int i = 0; i < ne; ++i) { float e = __expf(attnw[i][tid] - mx); attnw[i][tid] = e; sm += e; }
        float inv = 1.f / sm;
        for (int i = 0; i < ne; ++i) attnw[i][tid] *= inv;
      }
      __syncthreads();
      // ctx accumulate into cacc registers
      float t0 = 0.f, t1 = 0.f, t2 = 0.f;
      for (int i = 0; i < ne; ++i) {
        t0 += attnw[i][h0] * bf2f(Vl[i][tid]);
        t1 += attnw[i][h1] * bf2f(Vl[i][tid + 256]);
        t2 += attnw[i][h2] * bf2f(Vl[i][tid + 512]);
      }
      cc0 += t0; cc1 += t1; cc2 += t2;
      __syncthreads();  // attnw/q_s reuse next iteration
    }
  }

  // logits: l = tid>>2 (50 used), quarter qq = tid&3 over 192 d each, quad-reduce via shfl
  q_s[tid] = ac0; q_s[tid + 256] = ac1; q_s[tid + 512] = ac2;
  c_s[tid] = cc0; c_s[tid + 256] = cc1; c_s[tid + 512] = cc2;
  __syncthreads();
  const int l = tid >> 2, qq = tid & 3;
  float res = 0.f;
  if (l < NL) {
    const float* pr = predw + (size_t)l * DD;
    const float* wr = wop + (size_t)l * DD;
    const int dbeg = qq * 192;
#pragma unroll 4
    for (int d = dbeg; d < dbeg + 192; ++d)
      res += q_s[d] * pr[d] + c_s[d] * wr[d];
  }
  res += __shfl_xor(res, 1);
  res += __shfl_xor(res, 2);
  if (qq == 0 && l < NL) {
    float nuf = hasany ? (float)nu : 0.f;
    out[(size_t)b * NL + l] = predb[l] + (res + nuf * bop[l]) * (1.0f / 23.0f);
  }
}

// ---------------- host ----------------
extern "C" void kernel_launch(void* const* d_in, const int* in_sizes, int n_in,
                              void* d_out, int out_size, void* d_ws, size_t ws_size,
                              hipStream_t stream) {
  const float* cls  = (const float*)d_in[0];
  const float* mtab = (const float*)d_in[1];
  const float* ipw  = (const float*)d_in[2];
  const float* ipb  = (const float*)d_in[3];
  const float* opw  = (const float*)d_in[4];
  const float* opb  = (const float*)d_in[5];
  const float* pw   = (const float*)d_in[6];
  const float* pb   = (const float*)d_in[7];
  const int*   em   = (const int*)d_in[8];
  float* outp = (float*)d_out;
  (void)in_sizes; (void)n_in; (void)out_size;

  // ws layout: q_miss(70656) | wop(153600) | bop(pad 256) | KV chunk buffer
  char* ws = (char*)d_ws;
  float* q_miss = (float*)ws;
  float* wopb   = (float*)(ws + 70656);
  float* bopb   = (float*)(ws + 70656 + 153600);
  unsigned short* KVp = (unsigned short*)(ws + 224512);

  // chunk the batch so the KV buffer fits ws (chunk multiple of 128 keeps GEMM tiling exact)
  size_t per_sample = (size_t)NS * 1536 * 2;  // 70656 B
  int Bc = 128;
  if (ws_size > 224512) {
    size_t n = (ws_size - 224512) / per_sample;
    if (n > (size_t)NB) n = NB;
    int nn = (int)((n / 128) * 128);
    if (nn > Bc) Bc = nn;
  }

  k_qmiss<<<dim3(69), dim3(256), 0, stream>>>(ipw, ipb, mtab, q_miss);
  k_wop<<<dim3(150), dim3(256), 0, stream>>>(pw, opw, wopb);
  k_bop<<<dim3(1), dim3(64), 0, stream>>>(pw, opb, bopb);

  for (int b0 = 0; b0 < NB; b0 += Bc) {
    int bc = NB - b0; if (bc > Bc) bc = Bc;
    int Mrows = bc * NS;                       // multiple of 128
    dim3 g(Mrows / 128, 12);
    kv_gemm<<<g, dim3(256), 0, stream>>>(cls + (size_t)b0 * NS * DD,
                                         ipw + (size_t)DD * DD,  // K,V weight rows
                                         ipb + DD, KVp, Mrows);
    attn_logits<<<dim3(bc), dim3(256), 0, stream>>>(cls, mtab, KVp, q_miss, wopb, bopb,
                                                    pw, pb, em, outp, b0);
  }
}

// Round 2
// 1282.180 us; speedup vs baseline: 1.3499x; 1.3499x over previous
//
#include <hip/hip_runtime.h>
#include <hip/hip_bf16.h>
#include <stdint.h>

// Problem constants
#define DD   768
#define NS   23
#define NL   50
#define NB   4096

typedef float  floatx4 __attribute__((ext_vector_type(4)));
typedef __bf16 bf16x8  __attribute__((ext_vector_type(8)));

__device__ __forceinline__ unsigned short f2bf(float x) {
  unsigned int u = __float_as_uint(x);
  u += 0x7fffu + ((u >> 16) & 1u);          // RNE (inputs Gaussian, no NaN)
  return (unsigned short)(u >> 16);
}
__device__ __forceinline__ float bf2f(unsigned short v) {
  return __uint_as_float(((unsigned int)v) << 16);
}

// async 16B global->LDS (m97 pattern). LDS dest = wave-uniform base + lane*16.
__device__ __forceinline__ void gload_lds16(const void* g, void* s) {
  __builtin_amdgcn_global_load_lds((const __attribute__((address_space(1))) void*)g,
                                   (__attribute__((address_space(3))) void*)s, 16, 0, 0);
}

__device__ __forceinline__ float dot8bf(int4 a, int4 b) {
  union { int4 v; unsigned short s[8]; } ua, ub;
  ua.v = a; ub.v = b;
  float r = 0.f;
#pragma unroll
  for (int i = 0; i < 8; ++i) r += bf2f(ua.s[i]) * bf2f(ub.s[i]);
  return r;
}

// ---------------- precompute kernels (tiny, once per call) ----------------
// q_miss[s,d] (bf16) = in_proj_w[d,:] . missing_table[s,:] + in_proj_b[d]
__global__ void k_qmiss(const float* __restrict__ ipw, const float* __restrict__ ipb,
                        const float* __restrict__ mt, unsigned short* __restrict__ qm) {
  int o = blockIdx.x * 256 + threadIdx.x;   // 23*768 = 69*256 exact
  int s = o / DD, d = o - s * DD;
  const float* wr = ipw + (size_t)d * DD;
  const float* mr = mt + (size_t)s * DD;
  float sum = ipb[d];
  for (int j = 0; j < DD; ++j) sum += wr[j] * mr[j];
  qm[o] = f2bf(sum);
}

// wop[l,d] = sum_j pred_w[l,j] * out_proj_w[j,d]
__global__ void k_wop(const float* __restrict__ pw, const float* __restrict__ opw,
                      float* __restrict__ wop) {
  int o = blockIdx.x * 256 + threadIdx.x;   // 50*768 = 150*256 exact
  int l = o / DD, d = o - l * DD;
  const float* pr = pw + (size_t)l * DD;
  float sum = 0.f;
  for (int j = 0; j < DD; ++j) sum += pr[j] * opw[(size_t)j * DD + d];
  wop[o] = sum;
}

// bop[l] = pred_w[l,:] . out_proj_b
__global__ void k_bop(const float* __restrict__ pw, const float* __restrict__ opb,
                      float* __restrict__ bop) {
  int l = threadIdx.x;
  if (l < NL) {
    const float* pr = pw + (size_t)l * DD;
    float sum = 0.f;
    for (int j = 0; j < DD; ++j) sum += pr[j] * opb[j];
    bop[l] = sum;
  }
}

// K/V weight rows fp32 -> bf16 (1536*768 elements, 294912 float4)
__global__ void cast_w(const float* __restrict__ src, unsigned short* __restrict__ dst) {
  int i = blockIdx.x * 256 + threadIdx.x;   // 1152 blocks exact
  float4 v = *(const float4*)(src + (size_t)i * 4);
  ushort4 u;
  u.x = f2bf(v.x); u.y = f2bf(v.y); u.z = f2bf(v.z); u.w = f2bf(v.w);
  *(ushort4*)(dst + (size_t)i * 4) = u;
}

// ---------------- cls cast + masked per-sample row-sum ----------------
// Abf[bl,s,:] = bf16(cls[b,s,:]);  sumex[bl,:] = sum_{s exist} cls[b,s,:]
// (or sum_s mtab[s,:] when no section exists — matches reference has_any=false path)
__global__ __launch_bounds__(192) void cast_cls(
    const float* __restrict__ cls, const int* __restrict__ exist,
    const float* __restrict__ mtab, unsigned short* __restrict__ Abf,
    float* __restrict__ sumex, int b0) {
  const int bl = blockIdx.x, b = b0 + bl, t = threadIdx.x;
  __shared__ int em[NS];
  if (t < NS) em[t] = exist[(size_t)b * NS + t];
  __syncthreads();
  int any = 0;
  for (int s = 0; s < NS; ++s) any |= em[s];
  const int d = t * 4;
  float4 sum = {0.f, 0.f, 0.f, 0.f};
  for (int s = 0; s < NS; ++s) {
    float4 v = *(const float4*)(cls + ((size_t)b * NS + s) * DD + d);
    ushort4 u;
    u.x = f2bf(v.x); u.y = f2bf(v.y); u.z = f2bf(v.z); u.w = f2bf(v.w);
    *(ushort4*)(Abf + ((size_t)bl * NS + s) * DD + d) = u;
    if (em[s]) { sum.x += v.x; sum.y += v.y; sum.z += v.z; sum.w += v.w; }
  }
  if (!any) {
    for (int s = 0; s < NS; ++s) {
      float4 m = *(const float4*)(mtab + (size_t)s * DD + d);
      sum.x += m.x; sum.y += m.y; sum.z += m.z; sum.w += m.w;
    }
  }
  *(float4*)(sumex + (size_t)bl * DD + d) = sum;
}

// ---------------- K/V projection GEMM (m97 structure) ----------------
// C[m,0:768]=K, C[m,768:1536]=V (bf16). A bf16 [Mrows,768], W bf16 [1536,768] (row=out col).
// 128x128 tile, 4 waves of 4x4 16x16x32 MFMA, BK=32, global_load_lds width-16 staging.
// grid.x = N-tiles (12, fastest-varying -> A-tile temporal locality in L2/L3).
__global__ __launch_bounds__(256, 2) void kv_gemm(
    const unsigned short* __restrict__ A, const unsigned short* __restrict__ W,
    const float* __restrict__ bias, unsigned short* __restrict__ C) {
  __shared__ __align__(16) unsigned short As[128 * 32];
  __shared__ __align__(16) unsigned short Bs[128 * 32];
  const int tid = threadIdx.x;
  const int wave = tid >> 6, lane = tid & 63;
  const int wm = wave >> 1, wn = wave & 1;
  const int lq = lane >> 4, lr = lane & 15;

  floatx4 acc[4][4];
#pragma unroll
  for (int a = 0; a < 4; ++a)
#pragma unroll
    for (int b = 0; b < 4; ++b) {
      acc[a][b][0] = 0.f; acc[a][b][1] = 0.f; acc[a][b][2] = 0.f; acc[a][b][3] = 0.f;
    }

  // 512 16B-chunks per matrix per K-step: 2 issues/thread/matrix.
  // chunk c -> row r=c>>2, k-group kc=c&3; LDS dest contiguous in c (no padding!).
  const unsigned short* ga[2]; const unsigned short* gb[2];
  unsigned short* sa[2]; unsigned short* sb[2];
#pragma unroll
  for (int j = 0; j < 2; ++j) {
    int c = (wave * 2 + j) * 64 + lane;
    int r = c >> 2, kc = c & 3;
    ga[j] = A + ((size_t)blockIdx.y * 128 + r) * DD + kc * 8;
    gb[j] = W + ((size_t)blockIdx.x * 128 + r) * DD + kc * 8;
    sa[j] = &As[c * 8];
    sb[j] = &Bs[c * 8];
  }

  for (int k0 = 0; k0 < DD; k0 += 32) {
    gload_lds16(ga[0] + k0, sa[0]);
    gload_lds16(ga[1] + k0, sa[1]);
    gload_lds16(gb[0] + k0, sb[0]);
    gload_lds16(gb[1] + k0, sb[1]);
    __syncthreads();                          // drains vmcnt: staged data visible
    bf16x8 af[4], bq[4];
#pragma unroll
    for (int t = 0; t < 4; ++t) {
      af[t] = *(bf16x8*)&As[(wm * 64 + t * 16 + lr) * 32 + lq * 8];
      bq[t] = *(bf16x8*)&Bs[(wn * 64 + t * 16 + lr) * 32 + lq * 8];
    }
#pragma unroll
    for (int mt = 0; mt < 4; ++mt)
#pragma unroll
      for (int nt = 0; nt < 4; ++nt)
        acc[mt][nt] = __builtin_amdgcn_mfma_f32_16x16x32_bf16(af[mt], bq[nt], acc[mt][nt], 0, 0, 0);
    __syncthreads();
  }

  // epilogue: D[row=(lane>>4)*4+i][col=lane&15] (verified m89/m91 layout)
  const int bm = blockIdx.y * 128 + wm * 64;
  const int bn = blockIdx.x * 128 + wn * 64;
#pragma unroll
  for (int nt = 0; nt < 4; ++nt) {
    int col = bn + nt * 16 + lr;
    float bb = bias[col];
#pragma unroll
    for (int mt = 0; mt < 4; ++mt) {
#pragma unroll
      for (int i = 0; i < 4; ++i) {
        int row = bm + mt * 16 + lq * 4 + i;
        C[(size_t)row * 1536 + col] = f2bf(acc[mt][nt][i] + bb);
      }
    }
  }
}

// ---------------- per-sample attention + folded epilogue ----------------
// W-folding: W[k,h] = sum_{q missing} softmax(qK^T)[q,h,k]; ctx_sum[d] = sum_k W[k,h(d)] V[k,d].
// logits[b] = pred_b + (sumex.pred_w + ctx_sum.wop + nu*bop)/23
__global__ __launch_bounds__(256, 2) void attn_logits(
    const float* __restrict__ sumex, const unsigned short* __restrict__ KV,
    const unsigned short* __restrict__ qmb,
    const float* __restrict__ wop, const float* __restrict__ bop,
    const float* __restrict__ predw, const float* __restrict__ predb,
    const int* __restrict__ exist, float* __restrict__ out, int b0) {
  const int tid = threadIdx.x;
  const int bl = blockIdx.x;
  const int b = b0 + bl;

  __shared__ __align__(16) unsigned short Kl[NS][776]; // +8 pad: row=388 dw, 4-bank shift per row
  __shared__ float sc[NS][8][24];                      // scores/attn [qi][h][ki]
  __shared__ float Wk[NS][8];
  __shared__ __align__(16) float a_s[DD], c_s[DD];
  __shared__ int elist[NS], ulist[NS], meta[2];

  if (tid == 0) {
    int ne = 0, nu = 0;
    for (int s = 0; s < NS; ++s) {
      if (exist[(size_t)b * NS + s] != 0) elist[ne++] = s;
      else ulist[nu++] = s;
    }
    meta[0] = ne; meta[1] = nu;
  }
  __syncthreads();
  const int ne = meta[0], nu = meta[1];
  const int hasany = (ne > 0);

  // stage K rows of existing sections (compacted): ne*96 int4 chunks
  for (int c = tid; c < ne * 96; c += 256) {
    int i = c / 96, t = c - i * 96;
    *(int4*)&Kl[i][t * 8] = *(const int4*)(KV + ((size_t)bl * NS + elist[i]) * 1536 + t * 8);
  }
  __syncthreads();

  // scores: all nu*8*ne jobs across 256 threads; q from global bf16 (L2-hot 35KB table)
  const int nj = nu * 8 * ne;
  for (int c = tid; c < nj; c += 256) {
    int ki = c % ne, rest = c / ne;
    int h = rest & 7, qi = rest >> 3;
    const int4* kp = (const int4*)&Kl[ki][h * 96];
    const int4* qp = (const int4*)(qmb + (size_t)ulist[qi] * DD + h * 96);
    float s = 0.f;
#pragma unroll
    for (int c4 = 0; c4 < 12; ++c4) s += dot8bf(kp[c4], qp[c4]);
    sc[qi][h][ki] = s * 0.10206207261596575f;  // 96^-0.5
  }
  __syncthreads();

  // softmax per (qi,h) row over ne keys (masked keys excluded == exact 0 weight)
  for (int c = tid; c < nu * 8; c += 256) {
    int qi = c >> 3, h = c & 7;
    float* row = sc[qi][h];
    float mx = -1e30f;
    for (int i = 0; i < ne; ++i) mx = fmaxf(mx, row[i]);
    float sm = 0.f;
    for (int i = 0; i < ne; ++i) { float e = __expf(row[i] - mx); row[i] = e; sm += e; }
    float inv = 1.f / sm;
    for (int i = 0; i < ne; ++i) row[i] *= inv;
  }
  __syncthreads();

  // fold over queries: Wk[ki][h] = sum_qi attn  (zero when nu==0)
  for (int c = tid; c < ne * 8; c += 256) {
    int ki = c >> 3, h = c & 7;
    float s = 0.f;
    for (int qi = 0; qi < nu; ++qi) s += sc[qi][h][ki];
    Wk[ki][h] = s;
  }
  __syncthreads();

  // ctx accumulate (V streamed from global, used once) + acc from sumex
  const int d0 = tid, d1 = tid + 256, d2 = tid + 512;
  const int h0 = d0 / 96, h1 = d1 / 96, h2 = d2 / 96;
  float c0 = 0.f, c1 = 0.f, c2 = 0.f;
  for (int i = 0; i < ne; ++i) {
    const unsigned short* vp = KV + ((size_t)bl * NS + elist[i]) * 1536 + 768;
    float w0 = Wk[i][h0], w1 = Wk[i][h1], w2 = Wk[i][h2];
    c0 += w0 * bf2f(vp[d0]);
    c1 += w1 * bf2f(vp[d1]);
    c2 += w2 * bf2f(vp[d2]);
  }
  a_s[d0] = sumex[(size_t)bl * DD + d0];
  a_s[d1] = sumex[(size_t)bl * DD + d1];
  a_s[d2] = sumex[(size_t)bl * DD + d2];
  c_s[d0] = c0; c_s[d1] = c1; c_s[d2] = c2;
  __syncthreads();

  // logits: l = tid>>2, quarter qq = tid&3 over 192 dims, quad shfl reduce
  const int l = tid >> 2, qq = tid & 3;
  float res = 0.f;
  if (l < NL) {
    const float* pr = predw + (size_t)l * DD;
    const float* wr = wop + (size_t)l * DD;
    const int dbeg = qq * 192;
#pragma unroll 4
    for (int d = dbeg; d < dbeg + 192; ++d)
      res += a_s[d] * pr[d] + c_s[d] * wr[d];
  }
  res += __shfl_xor(res, 1);
  res += __shfl_xor(res, 2);
  if (qq == 0 && l < NL) {
    float nuf = hasany ? (float)nu : 0.f;
    out[(size_t)b * NL + l] = predb[l] + (res + nuf * bop[l]) * (1.0f / 23.0f);
  }
}

// ---------------- host ----------------
extern "C" void kernel_launch(void* const* d_in, const int* in_sizes, int n_in,
                              void* d_out, int out_size, void* d_ws, size_t ws_size,
                              hipStream_t stream) {
  const float* cls  = (const float*)d_in[0];
  const float* mtab = (const float*)d_in[1];
  const float* ipw  = (const float*)d_in[2];
  const float* ipb  = (const float*)d_in[3];
  const float* opw  = (const float*)d_in[4];
  const float* opb  = (const float*)d_in[5];
  const float* pw   = (const float*)d_in[6];
  const float* pb   = (const float*)d_in[7];
  const int*   em   = (const int*)d_in[8];
  float* outp = (float*)d_out;
  (void)in_sizes; (void)n_in; (void)out_size;

  // ws: qmiss_bf(35328) | wop(153600) | bop(256) | Wbf(2359296) | chunk{sumex,Abf,KV}
  char* ws = (char*)d_ws;
  unsigned short* qmb  = (unsigned short*)ws;
  float*          wopb = (float*)(ws + 35328);
  float*          bopb = (float*)(ws + 35328 + 153600);
  unsigned short* Wbf  = (unsigned short*)(ws + 189184);
  char* cb = ws + 2548480;
  const size_t fixed = 2548480;
  const size_t per   = 3072 + 35328 + 70656;  // sumex + Abf + KV per sample

  int Bc = 128;                                // chunk multiple of 128 (GEMM M-tiling exact)
  if (ws_size > fixed) {
    size_t n = (ws_size - fixed) / per;
    if (n > (size_t)NB) n = NB;
    int nn = (int)((n / 128) * 128);
    if (nn > Bc) Bc = nn;
  }

  k_qmiss<<<dim3(69),   dim3(256), 0, stream>>>(ipw, ipb, mtab, qmb);
  k_wop  <<<dim3(150),  dim3(256), 0, stream>>>(pw, opw, wopb);
  k_bop  <<<dim3(1),    dim3(64),  0, stream>>>(pw, opb, bopb);
  cast_w <<<dim3(1152), dim3(256), 0, stream>>>(ipw + (size_t)DD * DD, Wbf);

  for (int b0 = 0; b0 < NB; b0 += Bc) {
    int bc = NB - b0; if (bc > Bc) bc = Bc;
    float*          sumex = (float*)cb;
    unsigned short* Abf   = (unsigned short*)(cb + (size_t)bc * 3072);
    unsigned short* KVp   = (unsigned short*)(cb + (size_t)bc * (3072 + 35328));

    cast_cls<<<dim3(bc), dim3(192), 0, stream>>>(cls, em, mtab, Abf, sumex, b0);
    dim3 g(12, bc * NS / 128);                 // x = N-tiles fastest: A-tile locality
    kv_gemm<<<g, dim3(256), 0, stream>>>(Abf, Wbf, ipb + DD, KVp);
    attn_logits<<<dim3(bc), dim3(256), 0, stream>>>(sumex, KVp, qmb, wopb, bopb,
                                                    pw, pb, em, outp, b0);
  }
}

// Round 3
// 1129.080 us; speedup vs baseline: 1.5329x; 1.1356x over previous
//
#include <hip/hip_runtime.h>
#include <hip/hip_bf16.h>
#include <stdint.h>

// Problem constants
#define DD   768
#define NS   23
#define NL   50
#define NB   4096

typedef float  floatx4 __attribute__((ext_vector_type(4)));
typedef __bf16 bf16x8  __attribute__((ext_vector_type(8)));

__device__ __forceinline__ unsigned short f2bf(float x) {
  unsigned int u = __float_as_uint(x);
  u += 0x7fffu + ((u >> 16) & 1u);          // RNE (inputs Gaussian, no NaN)
  return (unsigned short)(u >> 16);
}
__device__ __forceinline__ float bf2f(unsigned short v) {
  return __uint_as_float(((unsigned int)v) << 16);
}

// async 16B global->LDS (m97 pattern). LDS dest = wave-uniform base + lane*16.
__device__ __forceinline__ void gload_lds16(const void* g, void* s) {
  __builtin_amdgcn_global_load_lds((const __attribute__((address_space(1))) void*)g,
                                   (__attribute__((address_space(3))) void*)s, 16, 0, 0);
}

// ---------------- precompute kernels (tiny, once per call) ----------------
// q_miss[s,d] (bf16) = in_proj_w[d,:] . missing_table[s,:] + in_proj_b[d]; rows 23..31 zero
__global__ void k_qmiss(const float* __restrict__ ipw, const float* __restrict__ ipb,
                        const float* __restrict__ mt, unsigned short* __restrict__ qm) {
  int o = blockIdx.x * 256 + threadIdx.x;   // 32*768 = 96*256 exact
  int s = o / DD, d = o - s * DD;
  if (s < NS) {
    const float* wr = ipw + (size_t)d * DD;
    const float* mr = mt + (size_t)s * DD;
    float sum = ipb[d];
    for (int j = 0; j < DD; ++j) sum += wr[j] * mr[j];
    qm[o] = f2bf(sum);
  } else {
    qm[o] = 0;
  }
}

// WT rows 0..767: predw^T, zero-padded to 64 cols
__global__ void k_pwT(const float* __restrict__ pw, float* __restrict__ WT) {
  int o = blockIdx.x * 256 + threadIdx.x;   // 768*64 = 192*256 exact
  int d = o >> 6, l = o & 63;
  WT[o] = (l < NL) ? pw[(size_t)l * DD + d] : 0.f;
}

// WT rows 768..1535: (pred_w @ out_proj_w)^T
__global__ void k_wopT(const float* __restrict__ pw, const float* __restrict__ opw,
                       float* __restrict__ WT) {
  int o = blockIdx.x * 256 + threadIdx.x;   // 50*768 = 150*256 exact
  int l = o / DD, d = o - l * DD;
  const float* pr = pw + (size_t)l * DD;
  float sum = 0.f;
  for (int j = 0; j < DD; ++j) sum += pr[j] * opw[(size_t)j * DD + d];
  WT[(size_t)(DD + d) * 64 + l] = sum;
}

// zero pad cols 50..63 of WT rows 768..1535
__global__ void k_wtz(float* __restrict__ WT) {
  int o = blockIdx.x * 256 + threadIdx.x;   // 768*14 = 10752 = 42*256 exact
  int d = o / 14, l = NL + (o - d * 14);
  WT[(size_t)(DD + d) * 64 + l] = 0.f;
}

// bop[l] = pred_w[l,:] . out_proj_b
__global__ void k_bop(const float* __restrict__ pw, const float* __restrict__ opb,
                      float* __restrict__ bop) {
  int l = threadIdx.x;
  if (l < NL) {
    const float* pr = pw + (size_t)l * DD;
    float sum = 0.f;
    for (int j = 0; j < DD; ++j) sum += pr[j] * opb[j];
    bop[l] = sum;
  }
}

// K/V weight rows fp32 -> bf16 (1536*768 elements, 294912 float4)
__global__ void cast_w(const float* __restrict__ src, unsigned short* __restrict__ dst) {
  int i = blockIdx.x * 256 + threadIdx.x;   // 1152 blocks exact
  float4 v = *(const float4*)(src + (size_t)i * 4);
  ushort4 u;
  u.x = f2bf(v.x); u.y = f2bf(v.y); u.z = f2bf(v.z); u.w = f2bf(v.w);
  *(ushort4*)(dst + (size_t)i * 4) = u;
}

// ---------------- cls cast + masked per-sample row-sum ----------------
__global__ __launch_bounds__(192) void cast_cls(
    const float* __restrict__ cls, const int* __restrict__ exist,
    const float* __restrict__ mtab, unsigned short* __restrict__ Abf,
    float* __restrict__ sumex, int b0) {
  const int bl = blockIdx.x, b = b0 + bl, t = threadIdx.x;
  __shared__ int em[NS];
  if (t < NS) em[t] = exist[(size_t)b * NS + t];
  __syncthreads();
  int any = 0;
  for (int s = 0; s < NS; ++s) any |= em[s];
  const int d = t * 4;
  float4 sum = {0.f, 0.f, 0.f, 0.f};
  for (int s = 0; s < NS; ++s) {
    float4 v = *(const float4*)(cls + ((size_t)b * NS + s) * DD + d);
    ushort4 u;
    u.x = f2bf(v.x); u.y = f2bf(v.y); u.z = f2bf(v.z); u.w = f2bf(v.w);
    *(ushort4*)(Abf + ((size_t)bl * NS + s) * DD + d) = u;
    if (em[s]) { sum.x += v.x; sum.y += v.y; sum.z += v.z; sum.w += v.w; }
  }
  if (!any) {
    for (int s = 0; s < NS; ++s) {
      float4 m = *(const float4*)(mtab + (size_t)s * DD + d);
      sum.x += m.x; sum.y += m.y; sum.z += m.z; sum.w += m.w;
    }
  }
  *(float4*)(sumex + (size_t)bl * DD + d) = sum;
}

// ---------------- K/V projection GEMM (m97 structure, unchanged) ----------------
__global__ __launch_bounds__(256, 2) void kv_gemm(
    const unsigned short* __restrict__ A, const unsigned short* __restrict__ W,
    const float* __restrict__ bias, unsigned short* __restrict__ C) {
  __shared__ __align__(16) unsigned short As[128 * 32];
  __shared__ __align__(16) unsigned short Bs[128 * 32];
  const int tid = threadIdx.x;
  const int wave = tid >> 6, lane = tid & 63;
  const int wm = wave >> 1, wn = wave & 1;
  const int lq = lane >> 4, lr = lane & 15;

  floatx4 acc[4][4];
#pragma unroll
  for (int a = 0; a < 4; ++a)
#pragma unroll
    for (int b = 0; b < 4; ++b) {
      acc[a][b][0] = 0.f; acc[a][b][1] = 0.f; acc[a][b][2] = 0.f; acc[a][b][3] = 0.f;
    }

  const unsigned short* ga[2]; const unsigned short* gb[2];
  unsigned short* sa[2]; unsigned short* sb[2];
#pragma unroll
  for (int j = 0; j < 2; ++j) {
    int c = (wave * 2 + j) * 64 + lane;
    int r = c >> 2, kc = c & 3;
    ga[j] = A + ((size_t)blockIdx.y * 128 + r) * DD + kc * 8;
    gb[j] = W + ((size_t)blockIdx.x * 128 + r) * DD + kc * 8;
    sa[j] = &As[c * 8];
    sb[j] = &Bs[c * 8];
  }

  for (int k0 = 0; k0 < DD; k0 += 32) {
    gload_lds16(ga[0] + k0, sa[0]);
    gload_lds16(ga[1] + k0, sa[1]);
    gload_lds16(gb[0] + k0, sb[0]);
    gload_lds16(gb[1] + k0, sb[1]);
    __syncthreads();
    bf16x8 af[4], bq[4];
#pragma unroll
    for (int t = 0; t < 4; ++t) {
      af[t] = *(bf16x8*)&As[(wm * 64 + t * 16 + lr) * 32 + lq * 8];
      bq[t] = *(bf16x8*)&Bs[(wn * 64 + t * 16 + lr) * 32 + lq * 8];
    }
#pragma unroll
    for (int mt = 0; mt < 4; ++mt)
#pragma unroll
      for (int nt = 0; nt < 4; ++nt)
        acc[mt][nt] = __builtin_amdgcn_mfma_f32_16x16x32_bf16(af[mt], bq[nt], acc[mt][nt], 0, 0, 0);
    __syncthreads();
  }

  const int bm = blockIdx.y * 128 + wm * 64;
  const int bn = blockIdx.x * 128 + wn * 64;
#pragma unroll
  for (int nt = 0; nt < 4; ++nt) {
    int col = bn + nt * 16 + lr;
    float bb = bias[col];
#pragma unroll
    for (int mt = 0; mt < 4; ++mt) {
#pragma unroll
      for (int i = 0; i < 4; ++i) {
        int row = bm + mt * 16 + lq * 4 + i;
        C[(size_t)row * 1536 + col] = f2bf(acc[mt][nt][i] + bb);
      }
    }
  }
}

// ---------------- attention: one wave per (sample, head); no LDS, no barriers ----
__global__ __launch_bounds__(256) void attn_ctx(
    const unsigned short* __restrict__ KV, const unsigned short* __restrict__ qmb,
    const int* __restrict__ exist, float* __restrict__ cvec,
    float* __restrict__ nuarr, int b0) {
  const int lane = threadIdx.x & 63;
  const int wgid = (blockIdx.x << 2) | (threadIdx.x >> 6);
  const int bl = wgid >> 3, h = wgid & 7;
  const int b = b0 + bl;
  const int lr = lane & 15, lq = lane >> 4;

  int ev = 0;
  if (lane < NS) ev = exist[(size_t)b * NS + lane];
  const unsigned long long emask = __ballot(lane < NS && ev != 0);
  const bool hasany = (emask != 0ull);
  if (h == 0 && lane == 0)
    nuarr[bl] = hasany ? (float)(NS - __popcll(emask)) : 0.f;

  // scores C[q][key]: 2x2 tiles of mfma 16x16x32 over the 96 head dims
  floatx4 acc[2][2];
#pragma unroll
  for (int mt = 0; mt < 2; ++mt)
#pragma unroll
    for (int nt = 0; nt < 2; ++nt) {
      acc[mt][nt][0] = 0.f; acc[mt][nt][1] = 0.f; acc[mt][nt][2] = 0.f; acc[mt][nt][3] = 0.f;
    }
  const unsigned short* qbase = qmb + h * 96;
  const unsigned short* kbase = KV + (size_t)bl * NS * 1536 + h * 96;
#pragma unroll
  for (int ks = 0; ks < 3; ++ks) {
    const int ko = ks * 32 + lq * 8;
    bf16x8 a0 = *(const bf16x8*)(qbase + (size_t)lr * DD + ko);
    bf16x8 a1 = *(const bf16x8*)(qbase + (size_t)(16 + lr) * DD + ko);
    bf16x8 b0 = *(const bf16x8*)(kbase + (size_t)lr * 1536 + ko);
    bf16x8 b1 = *(const bf16x8*)(kbase + (size_t)(16 + lr) * 1536 + ko);
    acc[0][0] = __builtin_amdgcn_mfma_f32_16x16x32_bf16(a0, b0, acc[0][0], 0, 0, 0);
    acc[0][1] = __builtin_amdgcn_mfma_f32_16x16x32_bf16(a0, b1, acc[0][1], 0, 0, 0);
    acc[1][0] = __builtin_amdgcn_mfma_f32_16x16x32_bf16(a1, b0, acc[1][0], 0, 0, 0);
    acc[1][1] = __builtin_amdgcn_mfma_f32_16x16x32_bf16(a1, b1, acc[1][1], 0, 0, 0);
  }

  // mask + per-row softmax (rows span the 16 lanes of a quad-group) + fold
  const float scale = 0.10206207261596575f;  // 96^-0.5
  const int c1 = 16 + lr;
  const bool v0 = (emask >> lr) & 1ull;
  const bool v1 = (c1 < NS) && ((emask >> c1) & 1ull);
  float wk0 = 0.f, wk1 = 0.f;
#pragma unroll
  for (int mt = 0; mt < 2; ++mt) {
#pragma unroll
    for (int i = 0; i < 4; ++i) {
      const int r = mt * 16 + lq * 4 + i;
      float s0 = v0 ? acc[mt][0][i] * scale : -1e30f;
      float s1 = v1 ? acc[mt][1][i] * scale : -1e30f;
      float mx = fmaxf(s0, s1);
      mx = fmaxf(mx, __shfl_xor(mx, 1));
      mx = fmaxf(mx, __shfl_xor(mx, 2));
      mx = fmaxf(mx, __shfl_xor(mx, 4));
      mx = fmaxf(mx, __shfl_xor(mx, 8));
      float e0 = __expf(s0 - mx), e1 = __expf(s1 - mx);
      float sm = e0 + e1;
      sm += __shfl_xor(sm, 1);
      sm += __shfl_xor(sm, 2);
      sm += __shfl_xor(sm, 4);
      sm += __shfl_xor(sm, 8);
      const bool rmiss = hasany && (r < NS) && !((emask >> r) & 1ull);
      float w = rmiss ? (1.f / sm) : 0.f;
      wk0 += e0 * w;
      wk1 += e1 * w;
    }
  }
  wk0 += __shfl_xor(wk0, 16); wk0 += __shfl_xor(wk0, 32);
  wk1 += __shfl_xor(wk1, 16); wk1 += __shfl_xor(wk1, 32);

  // ctx[d] = sum_k Wk[k] * V[k][d]; dims: lane (all), 64+lane (lanes<32 stored)
  const unsigned short* vbase = KV + (size_t)bl * NS * 1536 + 768 + h * 96;
  float ca = 0.f, cb = 0.f;
#pragma unroll 1
  for (int k = 0; k < NS; ++k) {
    float wkk = (k < 16) ? __shfl(wk0, k) : __shfl(wk1, k - 16);
    const unsigned short* vr = vbase + (size_t)k * 1536;
    ca += wkk * bf2f(vr[lane]);
    cb += wkk * bf2f(vr[64 + lane]);   // lanes>=32 overread into padded rows; discarded
  }
  float* co = cvec + (size_t)bl * DD + h * 96;
  co[lane] = ca;
  if (lane < 32) co[64 + lane] = cb;
}

// ---------------- logits: wave = 4 samples, lane = label ----------------
__global__ __launch_bounds__(256) void logits_k(
    const float* __restrict__ sumex, const float* __restrict__ cvec,
    const float* __restrict__ WT, const float* __restrict__ bop,
    const float* __restrict__ predb, const float* __restrict__ nuarr,
    float* __restrict__ out, int b0) {
  const int lane = threadIdx.x & 63;
  const int wv = (blockIdx.x << 2) | (threadIdx.x >> 6);
  const int s0 = wv * 4;
  float acc[4] = {0.f, 0.f, 0.f, 0.f};
  const float* xs[4]; const float* xc[4];
#pragma unroll
  for (int u = 0; u < 4; ++u) {
    xs[u] = sumex + (size_t)(s0 + u) * DD;
    xc[u] = cvec + (size_t)(s0 + u) * DD;
  }
  for (int d = 0; d < DD; d += 4) {
    float w0 = WT[(size_t)(d + 0) * 64 + lane];
    float w1 = WT[(size_t)(d + 1) * 64 + lane];
    float w2 = WT[(size_t)(d + 2) * 64 + lane];
    float w3 = WT[(size_t)(d + 3) * 64 + lane];
#pragma unroll
    for (int u = 0; u < 4; ++u) {
      float4 x = *(const float4*)(xs[u] + d);
      acc[u] += x.x * w0 + x.y * w1 + x.z * w2 + x.w * w3;
    }
  }
  for (int d = 0; d < DD; d += 4) {
    float w0 = WT[(size_t)(DD + d + 0) * 64 + lane];
    float w1 = WT[(size_t)(DD + d + 1) * 64 + lane];
    float w2 = WT[(size_t)(DD + d + 2) * 64 + lane];
    float w3 = WT[(size_t)(DD + d + 3) * 64 + lane];
#pragma unroll
    for (int u = 0; u < 4; ++u) {
      float4 x = *(const float4*)(xc[u] + d);
      acc[u] += x.x * w0 + x.y * w1 + x.z * w2 + x.w * w3;
    }
  }
  if (lane < NL) {
    float bo = bop[lane], pb = predb[lane];
#pragma unroll
    for (int u = 0; u < 4; ++u)
      out[(size_t)(b0 + s0 + u) * NL + lane] = pb + (acc[u] + nuarr[s0 + u] * bo) * (1.0f / 23.0f);
  }
}

// ---------------- host ----------------
extern "C" void kernel_launch(void* const* d_in, const int* in_sizes, int n_in,
                              void* d_out, int out_size, void* d_ws, size_t ws_size,
                              hipStream_t stream) {
  const float* cls  = (const float*)d_in[0];
  const float* mtab = (const float*)d_in[1];
  const float* ipw  = (const float*)d_in[2];
  const float* ipb  = (const float*)d_in[3];
  const float* opw  = (const float*)d_in[4];
  const float* opb  = (const float*)d_in[5];
  const float* pw   = (const float*)d_in[6];
  const float* pb   = (const float*)d_in[7];
  const int*   em   = (const int*)d_in[8];
  float* outp = (float*)d_out;
  (void)in_sizes; (void)n_in; (void)out_size;

  // fixed ws: qmb 32x768 bf16 (49152) | WT 1536x64 f32 (393216) | bop (256) | Wbf 1536x768 bf16 (2359296)
  char* ws = (char*)d_ws;
  unsigned short* qmb  = (unsigned short*)ws;
  float*          WT   = (float*)(ws + 49152);
  float*          bopb = (float*)(ws + 49152 + 393216);
  unsigned short* Wbf  = (unsigned short*)(ws + 49152 + 393216 + 256);
  const size_t fixed = 49152 + 393216 + 256 + 2359296;   // 2801920
  char* cb = ws + fixed;
  const size_t kvpad = 16 * 1536 * 2;                    // MFMA/ctx tail overread pad
  const size_t per   = 3072 + 35328 + 70656 + 3072 + 4;  // sumex+Abf+KV+cvec+nuarr

  int Bc = 128;
  if (ws_size > fixed + kvpad) {
    size_t n = (ws_size - fixed - kvpad) / per;
    if (n > (size_t)NB) n = NB;
    int nn = (int)((n / 128) * 128);
    if (nn > Bc) Bc = nn;
  }

  k_qmiss<<<dim3(96),   dim3(256), 0, stream>>>(ipw, ipb, mtab, qmb);
  k_pwT  <<<dim3(192),  dim3(256), 0, stream>>>(pw, WT);
  k_wopT <<<dim3(150),  dim3(256), 0, stream>>>(pw, opw, WT);
  k_wtz  <<<dim3(42),   dim3(256), 0, stream>>>(WT);
  k_bop  <<<dim3(1),    dim3(64),  0, stream>>>(pw, opb, bopb);
  cast_w <<<dim3(1152), dim3(256), 0, stream>>>(ipw + (size_t)DD * DD, Wbf);

  for (int b0 = 0; b0 < NB; b0 += Bc) {
    int bc = NB - b0; if (bc > Bc) bc = Bc;
    float*          sumex = (float*)cb;
    unsigned short* Abf   = (unsigned short*)(cb + (size_t)bc * 3072);
    unsigned short* KVp   = (unsigned short*)(cb + (size_t)bc * (3072 + 35328));
    float*          cvec  = (float*)(cb + (size_t)bc * (3072 + 35328 + 70656) + kvpad);
    float*          nuarr = (float*)(cb + (size_t)bc * (3072 + 35328 + 70656 + 3072) + kvpad);

    cast_cls<<<dim3(bc), dim3(192), 0, stream>>>(cls, em, mtab, Abf, sumex, b0);
    dim3 g(12, bc * NS / 128);
    kv_gemm<<<g, dim3(256), 0, stream>>>(Abf, Wbf, ipb + DD, KVp);
    attn_ctx<<<dim3(bc * 2), dim3(256), 0, stream>>>(KVp, qmb, em, cvec, nuarr, b0);
    logits_k<<<dim3(bc / 16), dim3(256), 0, stream>>>(sumex, cvec, WT, bopb, pb, nuarr, outp, b0);
  }
}